// Round 10
// baseline (244.181 us; speedup 1.0000x reference)
//
#include <hip/hip_runtime.h>
#include <hip/hip_bf16.h>
#include <math.h>

#define Bb 4
#define Nn 2048
#define Ee 768
#define Hh 12
#define Dd 64
#define RD 32
#define EPSf 1e-6f
#define NEG_BIG -3.0e38f
#define NTQB 16   // number of 128-row q blocks per (b,h)

#define NB_PREP  (Bb * Nn * 3 / 4)             // 6144: wave = (b, n, head-quad)
#define NB_VT    (Bb * Hh * 32)                // 1536
#define NB_WCONV (Ee * Ee / 4 / 256)           // 576

typedef __attribute__((ext_vector_type(8))) short short8;
typedef __attribute__((ext_vector_type(4))) float f32x4;

// scalar round-to-nearest-even fp32 -> bf16 bits (cheap kernels only)
__device__ inline unsigned f2bf(float x) {
    union { float f; unsigned u; } c; c.f = x;
    unsigned r = c.u + 0x7FFFu + ((c.u >> 16) & 1u);
    return r >> 16;
}

// packed fp32x2 -> bf16x2 (v_cvt_pk_bf16_f32)
__device__ inline unsigned pk_bf16(float a, float b) {
    union { __hip_bfloat162 h; unsigned u; } c;
    c.h = __float22bfloat162_rn(float2{a, b});
    return c.u;
}

// async global->LDS DMA, 16 B per lane; lds dest = uniform base + lane*16
__device__ inline void gload16(const void* g, void* l) {
    __builtin_amdgcn_global_load_lds(
        (const __attribute__((address_space(1))) void*)g,
        (__attribute__((address_space(3))) void*)l,
        16, 0, 0);
}

// ONE fused pre-pass kernel. [round-9 verified]
//  blocks [0, NB_PREP): RMS-norm + xPos rope, VECTORIZED: one wave per
//      (b, n, head-quad), float4 per lane (16 B loads). Rotation pairs are
//      thread-local (even/odd elems in-lane): no shfls for rotate_half.
//      RMS reduce = 4 shfl_xor within 16-lane head groups. uint2 stores.
//  blocks [NB_PREP, +NB_VT): V transpose (B,N,E) fp32 -> (B,H,D,N) bf16,
//      uint (2-key) packed stores.
//  blocks [+NB_WCONV): proj W fp32 -> bf16 convert.
__global__ __launch_bounds__(256) void prep_all(
    const float* __restrict__ q, const float* __restrict__ k,
    const float* __restrict__ qscale, const float* __restrict__ kscale,
    unsigned short* __restrict__ qn, unsigned short* __restrict__ kn,
    const float* __restrict__ v, unsigned short* __restrict__ vt,
    const float* __restrict__ w, unsigned short* __restrict__ wb)
{
    __shared__ float Vl[64 * 65];
    int bx = blockIdx.x;
    int t = threadIdx.x;
    if (bx < NB_PREP) {
        // ---- prep: one wave per (b, n, head-quad); lane owns 4 dims ----
        int wid = bx * 4 + (t >> 6);
        int lane = t & 63;
        int hq = wid % 3;                  // head-quad 0..2 (4 heads each)
        int bn = wid / 3;
        int n  = bn % Nn;
        int b  = bn / Nn;
        int h  = hq * 4 + (lane >> 4);     // head for this 16-lane group
        int d0 = (lane & 15) * 4;          // first dim of this lane's 4
        size_t g4 = (size_t)(b * Nn + n) * (Ee / 4) + hq * 64 + lane;
        float4 xq = ((const float4*)q)[g4];
        float4 xk = ((const float4*)k)[g4];
        float4 qs = ((const float4*)qscale)[lane & 15];
        float4 ks = ((const float4*)kscale)[lane & 15];
        float ssq = xq.x * xq.x + xq.y * xq.y + xq.z * xq.z + xq.w * xq.w;
        float ssk = xk.x * xk.x + xk.y * xk.y + xk.z * xk.z + xk.w * xk.w;
        #pragma unroll
        for (int m = 1; m < 16; m <<= 1) {
            ssq += __shfl_xor(ssq, m, 64);
            ssk += __shfl_xor(ssk, m, 64);
        }
        float rq = rsqrtf(ssq * (1.0f / 64.0f) + EPSf);
        float rk = rsqrtf(ssk * (1.0f / 64.0f) + EPSf);
        float oq[4], ok[4];
        oq[0] = xq.x * qs.x * rq; oq[1] = xq.y * qs.y * rq;
        oq[2] = xq.z * qs.z * rq; oq[3] = xq.w * qs.w * rq;
        ok[0] = xk.x * ks.x * rk; ok[1] = xk.y * ks.y * rk;
        ok[2] = xk.z * ks.z * rk; ok[3] = xk.w * ks.w * rk;
        if (d0 < RD) {                     // two rope pairs, thread-local
            float pw = ((float)n - (float)(Nn / 2)) * (1.0f / 512.0f);
            #pragma unroll
            for (int p = 0; p < 2; ++p) {
                int i = (d0 >> 1) + p;
                float invf = exp2f(-0.83048202372184f * (float)i);
                float ang  = (float)n * invf;
                float c = cosf(ang), s = sinf(ang);
                float base = (2.0f * (float)i + 12.8f) * (1.0f / 44.8f);
                float e  = pw * log2f(base);
                float sc = exp2f(e), rsc = exp2f(-e);
                float a = oq[2 * p], bq = oq[2 * p + 1];
                oq[2 * p]     = (a * c - bq * s) * sc;
                oq[2 * p + 1] = (bq * c + a * s) * sc;
                float ak = ok[2 * p], bk = ok[2 * p + 1];
                ok[2 * p]     = (ak * c - bk * s) * rsc;
                ok[2 * p + 1] = (bk * c + ak * s) * rsc;
            }
        }
        const float SCL = 0.125f * 1.44269504088896f;   // 1/sqrt(D) * log2(e)
        size_t o = ((size_t)(b * Hh + h) * Nn + n) * Dd + d0;
        uint2 uq, uk;
        uq.x = pk_bf16(oq[0] * SCL, oq[1] * SCL);
        uq.y = pk_bf16(oq[2] * SCL, oq[3] * SCL);
        uk.x = pk_bf16(ok[0], ok[1]);
        uk.y = pk_bf16(ok[2], ok[3]);
        *(uint2*)(qn + o) = uq;
        *(uint2*)(kn + o) = uk;
    } else if (bx < NB_PREP + NB_VT) {
        // ---- vt: V transpose, packed uint stores ----
        int vb = bx - NB_PREP;
        int bh = vb >> 5;
        int n0 = (vb & 31) * 64;
        int b = bh / Hh, h = bh % Hh;
        const float4* v4 = (const float4*)v;
        #pragma unroll
        for (int c = 0; c < 4; ++c) {
            int idx = t + c * 256;
            int n = idx >> 4, d4 = idx & 15;
            float4 vv = v4[(size_t)(b * Nn + n0 + n) * (Ee / 4) + h * 16 + d4];
            int la = n * 65 + d4 * 4;
            Vl[la] = vv.x; Vl[la + 1] = vv.y; Vl[la + 2] = vv.z; Vl[la + 3] = vv.w;
        }
        __syncthreads();
        #pragma unroll
        for (int c = 0; c < 8; ++c) {
            int linear = t + c * 256;          // 2048 = 64 d x 32 n-pairs
            int d = linear >> 5, n = (linear & 31) * 2;
            unsigned u = pk_bf16(Vl[n * 65 + d], Vl[(n + 1) * 65 + d]);
            *(unsigned*)(vt + ((size_t)bh * Dd + d) * Nn + n0 + n) = u;
        }
    } else {
        // ---- W fp32 -> bf16 convert ----
        int idx = (bx - NB_PREP - NB_VT) * 256 + t;   // one float4 each
        float4 vv = ((const float4*)w)[idx];
        uint2 uu;
        uu.x = pk_bf16(vv.x, vv.y);
        uu.y = pk_bf16(vv.z, vv.w);
        *(uint2*)(wb + (size_t)idx * 4) = uu;
    }
}

// MFMA flash attention (causal), NO-MAX softmax, WIDE q per wave,
// K/V READ DIRECT FROM L2 (no LDS staging, NO BARRIERS).
// K+V per (b,h) = 512 KB; 6 bh per XCD = 3 MB fits the 4 MB per-XCD L2
// (grid maps bh%8 -> XCD). Each wave loads its MFMA fragments straight
// from global: a0 = K[j0+col+16mt][quad*8], a1 = +32 (16 B, 16-B aligned).
// This removes the ~80%-saturated LDS pipe traffic (16 b128/wave/tile) AND
// the per-tile vmcnt(0)+barrier convoy. LDS keeps only the 16 KB P scratch
// (per-wave, race-free without syncs). Waves free-run; waves 0,1 skip the
// final fully-masked tile outright.
// QBLK=128 per block: 4 waves x 32 q (two 16-q groups A/B per wave).
// Row-sum l via MFMA with all-ones A operand. Heavy-first dispatch.
__global__ __launch_bounds__(256) void attn_kernel(
    const unsigned short* __restrict__ qn, const unsigned short* __restrict__ kn,
    const unsigned short* __restrict__ vt, unsigned short* __restrict__ y)
{
    __shared__ __align__(16) unsigned short Pl[8][16 * 64];    // per (wave,group)
    int t = threadIdx.x;
    int w = t >> 6, lane = t & 63;
    int quad = lane >> 4, col = lane & 15;
    int bh = blockIdx.x;
    int b = bh / Hh, h = bh % Hh;
    int qt = (NTQB - 1) - (int)blockIdx.y;     // heavy blocks dispatched first
    const unsigned short* kbh = kn + (size_t)bh * Nn * Dd;
    const unsigned short* vbh = vt + (size_t)bh * Dd * Nn;
    unsigned short* PlA = Pl[w * 2];
    unsigned short* PlB = Pl[w * 2 + 1];

    int sw = col & 7;

    int q0 = qt * 128;
    int qgA = q0 + w * 32;                  // group A min row (wave-uniform)
    int qArow = qgA + col;
    int qBrow = qArow + 16;
    const unsigned short* qpA = qn + ((size_t)bh * Nn + qArow) * Dd;
    short8 qf0A = *(const short8*)(qpA + quad * 8);
    short8 qf1A = *(const short8*)(qpA + 32 + quad * 8);
    const unsigned short* qpB = qpA + 16 * Dd;
    short8 qf0B = *(const short8*)(qpB + quad * 8);
    short8 qf1B = *(const short8*)(qpB + 32 + quad * 8);

    short8 ones;                            // bf16 1.0 in all 8 slots
    #pragma unroll
    for (int i = 0; i < 8; ++i) ones[i] = (short)0x3F80;

    const f32x4 Zc = (f32x4){0.f, 0.f, 0.f, 0.f};
    f32x4 OA[4], OB[4], LsA = Zc, LsB = Zc;
    #pragma unroll
    for (int i = 0; i < 4; ++i) { OA[i] = Zc; OB[i] = Zc; }
    // waves 0,1: rows < q0+64, so the final tile (keys q0+64..q0+127) is
    // fully masked -> skip it entirely (no barriers to honor).
    int ntiles = 2 * qt + 2 - (w < 2 ? 1 : 0);

    for (int tile = 0; tile < ntiles; ++tile) {
        int j0 = tile * 64;

        // S^T = K . Q^T for both q-groups; K fragments from L2, used twice.
        f32x4 SA[4], SB[4];
        __builtin_amdgcn_s_setprio(1);
        #pragma unroll
        for (int mt = 0; mt < 4; ++mt) {
            const unsigned short* kp = kbh + ((size_t)(j0 + col + 16 * mt) << 6);
            short8 a0 = *(const short8*)(kp + quad * 8);
            short8 a1 = *(const short8*)(kp + 32 + quad * 8);
            SA[mt] = __builtin_amdgcn_mfma_f32_16x16x32_bf16(a0, qf0A, Zc, 0, 0, 0);
            SA[mt] = __builtin_amdgcn_mfma_f32_16x16x32_bf16(a1, qf1A, SA[mt], 0, 0, 0);
            SB[mt] = __builtin_amdgcn_mfma_f32_16x16x32_bf16(a0, qf0B, Zc, 0, 0, 0);
            SB[mt] = __builtin_amdgcn_mfma_f32_16x16x32_bf16(a1, qf1B, SB[mt], 0, 0, 0);
        }
        __builtin_amdgcn_s_setprio(0);
        if (j0 + 63 > qgA) {               // diagonal for group A
            #pragma unroll
            for (int mt = 0; mt < 4; ++mt)
                #pragma unroll
                for (int r = 0; r < 4; ++r) {
                    int key = j0 + mt * 16 + quad * 4 + r;
                    if (key > qArow) SA[mt][r] = NEG_BIG;
                }
        }
        if (j0 + 63 > qgA + 16) {          // diagonal for group B
            #pragma unroll
            for (int mt = 0; mt < 4; ++mt)
                #pragma unroll
                for (int r = 0; r < 4; ++r) {
                    int key = j0 + mt * 16 + quad * 4 + r;
                    if (key > qBrow) SB[mt][r] = NEG_BIG;
                }
        }
        // no-max softmax: P = exp2(S); pack to per-group LDS scratch
        #pragma unroll
        for (int mt = 0; mt < 4; ++mt) {
            uint2 ua, ub;
            ua.x = pk_bf16(exp2f(SA[mt][0]), exp2f(SA[mt][1]));
            ua.y = pk_bf16(exp2f(SA[mt][2]), exp2f(SA[mt][3]));
            ub.x = pk_bf16(exp2f(SB[mt][0]), exp2f(SB[mt][1]));
            ub.y = pk_bf16(exp2f(SB[mt][2]), exp2f(SB[mt][3]));
            int pidx = col * 64 + (((2 * mt + (quad >> 1)) ^ sw) << 3) + ((quad & 1) << 2);
            *(uint2*)(PlA + pidx) = ua;
            *(uint2*)(PlB + pidx) = ub;
        }
        asm volatile("s_waitcnt lgkmcnt(0)" ::: "memory");
        int pr0 = col * 64 + ((quad ^ sw) << 3);
        int pr1 = col * 64 + (((quad + 4) ^ sw) << 3);
        short8 pfA0 = *(const short8*)(PlA + pr0);
        short8 pfA1 = *(const short8*)(PlA + pr1);
        short8 pfB0 = *(const short8*)(PlB + pr0);
        short8 pfB1 = *(const short8*)(PlB + pr1);
        // row sums via MFMA with all-ones A: every lane gets l for q=col
        LsA = __builtin_amdgcn_mfma_f32_16x16x32_bf16(ones, pfA0, LsA, 0, 0, 0);
        LsA = __builtin_amdgcn_mfma_f32_16x16x32_bf16(ones, pfA1, LsA, 0, 0, 0);
        LsB = __builtin_amdgcn_mfma_f32_16x16x32_bf16(ones, pfB0, LsB, 0, 0, 0);
        LsB = __builtin_amdgcn_mfma_f32_16x16x32_bf16(ones, pfB1, LsB, 0, 0, 0);
        // O^T += V^T . P^T; V fragments from L2, used twice.
        __builtin_amdgcn_s_setprio(1);
        #pragma unroll
        for (int mt = 0; mt < 4; ++mt) {
            const unsigned short* vp = vbh + (size_t)(col + 16 * mt) * Nn + j0;
            short8 a0 = *(const short8*)(vp + quad * 8);
            short8 a1 = *(const short8*)(vp + 32 + quad * 8);
            OA[mt] = __builtin_amdgcn_mfma_f32_16x16x32_bf16(a0, pfA0, OA[mt], 0, 0, 0);
            OA[mt] = __builtin_amdgcn_mfma_f32_16x16x32_bf16(a1, pfA1, OA[mt], 0, 0, 0);
            OB[mt] = __builtin_amdgcn_mfma_f32_16x16x32_bf16(a0, pfB0, OB[mt], 0, 0, 0);
            OB[mt] = __builtin_amdgcn_mfma_f32_16x16x32_bf16(a1, pfB1, OB[mt], 0, 0, 0);
        }
        __builtin_amdgcn_s_setprio(0);
    }
    float rlA = 1.0f / LsA[0];
    float rlB = 1.0f / LsB[0];
    unsigned short* ypA = y + ((size_t)(b * Nn + qArow)) * Ee + h * Dd;
    unsigned short* ypB = y + ((size_t)(b * Nn + qBrow)) * Ee + h * Dd;
    #pragma unroll
    for (int mt = 0; mt < 4; ++mt) {
        f32x4 oa = OA[mt] * rlA;
        f32x4 ob = OB[mt] * rlB;
        uint2 ua, ub;
        ua.x = pk_bf16(oa[0], oa[1]);
        ua.y = pk_bf16(oa[2], oa[3]);
        ub.x = pk_bf16(ob[0], ob[1]);
        ub.y = pk_bf16(ob[2], ob[3]);
        *(uint2*)(ypA + mt * 16 + quad * 4) = ua;
        *(uint2*)(ypB + mt * 16 + quad * 4) = ub;
    }
}

// MFMA NT GEMM: out[m][e] = sum_f y[m][f]*W[e][f] + bias[e]
// [round-6 verified version] 64(m) x 128(e) tile, BK=64, double-buffered
// async-DMA staging (one barrier per k-step), XOR swizzle, grid (6,128).
// Wave wv owns e-range wv*32: acc[mi 0..3][ni 0..1].
__global__ __launch_bounds__(256) void proj_kernel(
    const unsigned short* __restrict__ y, const unsigned short* __restrict__ w,
    const float* __restrict__ bias, float* __restrict__ out)
{
    __shared__ __align__(16) unsigned short Al[2][64 * 64];
    __shared__ __align__(16) unsigned short Bl[2][128 * 64];
    int t = threadIdx.x;
    int wv = t >> 6, lane = t & 63;
    int quad = lane >> 4, col = lane & 15;
    int e0 = blockIdx.x * 128, m0 = blockIdx.y * 64;
    int l8 = lane >> 3, c8 = lane & 7;
    int g8 = (c8 ^ l8) * 8;
    f32x4 acc[4][2];
    #pragma unroll
    for (int i = 0; i < 4; ++i)
        #pragma unroll
        for (int j = 0; j < 2; ++j) acc[i][j] = (f32x4){0.f, 0.f, 0.f, 0.f};

    // prologue: stage k0 = 0 into buffer 0
    #pragma unroll
    for (int c = 0; c < 2; ++c) {
        int r = wv * 16 + c * 8 + l8;
        gload16(y + (size_t)(m0 + r) * Ee + g8, &Al[0][(wv * 16 + c * 8) * 64]);
    }
    #pragma unroll
    for (int c = 0; c < 4; ++c) {
        int r = wv * 32 + c * 8 + l8;
        gload16(w + (size_t)(e0 + r) * Ee + g8, &Bl[0][(wv * 32 + c * 8) * 64]);
    }

    for (int ks = 0; ks < Ee / 64; ++ks) {
        int cur = ks & 1;
        asm volatile("s_waitcnt vmcnt(0)" ::: "memory");
        __syncthreads();
        if (ks + 1 < Ee / 64) {            // prefetch next k-tile
            int k0n = (ks + 1) * 64;
            #pragma unroll
            for (int c = 0; c < 2; ++c) {
                int r = wv * 16 + c * 8 + l8;
                gload16(y + (size_t)(m0 + r) * Ee + k0n + g8,
                        &Al[cur ^ 1][(wv * 16 + c * 8) * 64]);
            }
            #pragma unroll
            for (int c = 0; c < 4; ++c) {
                int r = wv * 32 + c * 8 + l8;
                gload16(w + (size_t)(e0 + r) * Ee + k0n + g8,
                        &Bl[cur ^ 1][(wv * 32 + c * 8) * 64]);
            }
        }
        __builtin_amdgcn_s_setprio(1);
        #pragma unroll
        for (int kc = 0; kc < 2; ++kc) {
            short8 a[4], bb[2];
            #pragma unroll
            for (int mi = 0; mi < 4; ++mi) {
                int row = mi * 16 + col;
                int sl = ((kc * 4 + quad) ^ (row & 7)) * 8;
                a[mi] = *(const short8*)(&Al[cur][row * 64 + sl]);
            }
            #pragma unroll
            for (int ni = 0; ni < 2; ++ni) {
                int row = wv * 32 + ni * 16 + col;
                int sl = ((kc * 4 + quad) ^ (row & 7)) * 8;
                bb[ni] = *(const short8*)(&Bl[cur][row * 64 + sl]);
            }
            #pragma unroll
            for (int mi = 0; mi < 4; ++mi)
                #pragma unroll
                for (int ni = 0; ni < 2; ++ni)
                    acc[mi][ni] = __builtin_amdgcn_mfma_f32_16x16x32_bf16(a[mi], bb[ni], acc[mi][ni], 0, 0, 0);
        }
        __builtin_amdgcn_s_setprio(0);
    }
    // C layout: e-col = col, m-row = quad*4 + r
    #pragma unroll
    for (int ni = 0; ni < 2; ++ni) {
        int e = e0 + wv * 32 + ni * 16 + col;
        float be = bias[e];
        #pragma unroll
        for (int mi = 0; mi < 4; ++mi) {
            int mrow = m0 + mi * 16 + quad * 4;
            #pragma unroll
            for (int r = 0; r < 4; ++r)
                out[(size_t)(mrow + r) * Ee + e] = acc[mi][ni][r] + be;
        }
    }
}

extern "C" void kernel_launch(void* const* d_in, const int* in_sizes, int n_in,
                              void* d_out, int out_size, void* d_ws, size_t ws_size,
                              hipStream_t stream) {
    const float* q      = (const float*)d_in[0];
    const float* k      = (const float*)d_in[1];
    const float* v      = (const float*)d_in[2];
    const float* qscale = (const float*)d_in[3];
    const float* kscale = (const float*)d_in[4];
    const float* projw  = (const float*)d_in[5];
    const float* projb  = (const float*)d_in[6];
    float* out = (float*)d_out;

    char* base = (char*)d_ws;
    unsigned short* qn   = (unsigned short*)(base + 393216);
    unsigned short* kn   = (unsigned short*)(base + 12976128);
    unsigned short* vt   = (unsigned short*)(base + 25559040);
    unsigned short* yatt = (unsigned short*)(base + 38141952);
    unsigned short* wb   = (unsigned short*)(base + 50724864);

    prep_all<<<NB_PREP + NB_VT + NB_WCONV, 256, 0, stream>>>(
        q, k, qscale, kscale, qn, kn, v, vt, projw, wb);

    dim3 agrid(Bb * Hh, NTQB);                           // (48, 16): bh -> XCD
    attn_kernel<<<agrid, 256, 0, stream>>>(qn, kn, vt, yatt);

    dim3 ggrid(Ee / 128, (Bb * Nn) / 64);                // (6, 128)
    proj_kernel<<<ggrid, 256, 0, stream>>>(yatt, wb, projb, out);
}

// Round 11
// 190.592 us; speedup vs baseline: 1.2812x; 1.2812x over previous
//
#include <hip/hip_runtime.h>
#include <hip/hip_bf16.h>
#include <math.h>

#define Bb 4
#define Nn 2048
#define Ee 768
#define Hh 12
#define Dd 64
#define RD 32
#define EPSf 1e-6f
#define NEG_BIG -3.0e38f
#define NTQB 16   // number of 128-row q blocks per (b,h)

#define NB_PREP  (Bb * Nn * 3 / 4)             // 6144: wave = (b, n, head-quad)
#define NB_VT    (Bb * Hh * 32)                // 1536
#define NB_WCONV (Ee * Ee / 4 / 256)           // 576

typedef __attribute__((ext_vector_type(8))) short short8;
typedef __attribute__((ext_vector_type(4))) float f32x4;

// scalar round-to-nearest-even fp32 -> bf16 bits (cheap kernels only)
__device__ inline unsigned f2bf(float x) {
    union { float f; unsigned u; } c; c.f = x;
    unsigned r = c.u + 0x7FFFu + ((c.u >> 16) & 1u);
    return r >> 16;
}

// packed fp32x2 -> bf16x2 (v_cvt_pk_bf16_f32)
__device__ inline unsigned pk_bf16(float a, float b) {
    union { __hip_bfloat162 h; unsigned u; } c;
    c.h = __float22bfloat162_rn(float2{a, b});
    return c.u;
}

// async global->LDS DMA, 16 B per lane; lds dest = uniform base + lane*16
__device__ inline void gload16(const void* g, void* l) {
    __builtin_amdgcn_global_load_lds(
        (const __attribute__((address_space(1))) void*)g,
        (__attribute__((address_space(3))) void*)l,
        16, 0, 0);
}

// ONE fused pre-pass kernel. [round-9 verified]
//  blocks [0, NB_PREP): RMS-norm + xPos rope, VECTORIZED: one wave per
//      (b, n, head-quad), float4 per lane (16 B loads). Rotation pairs are
//      thread-local (even/odd elems in-lane): no shfls for rotate_half.
//      RMS reduce = 4 shfl_xor within 16-lane head groups. uint2 stores.
//  blocks [NB_PREP, +NB_VT): V transpose (B,N,E) fp32 -> (B,H,D,N) bf16,
//      uint (2-key) packed stores.
//  blocks [+NB_WCONV): proj W fp32 -> bf16 convert.
__global__ __launch_bounds__(256) void prep_all(
    const float* __restrict__ q, const float* __restrict__ k,
    const float* __restrict__ qscale, const float* __restrict__ kscale,
    unsigned short* __restrict__ qn, unsigned short* __restrict__ kn,
    const float* __restrict__ v, unsigned short* __restrict__ vt,
    const float* __restrict__ w, unsigned short* __restrict__ wb)
{
    __shared__ float Vl[64 * 65];
    int bx = blockIdx.x;
    int t = threadIdx.x;
    if (bx < NB_PREP) {
        // ---- prep: one wave per (b, n, head-quad); lane owns 4 dims ----
        int wid = bx * 4 + (t >> 6);
        int lane = t & 63;
        int hq = wid % 3;                  // head-quad 0..2 (4 heads each)
        int bn = wid / 3;
        int n  = bn % Nn;
        int b  = bn / Nn;
        int h  = hq * 4 + (lane >> 4);     // head for this 16-lane group
        int d0 = (lane & 15) * 4;          // first dim of this lane's 4
        size_t g4 = (size_t)(b * Nn + n) * (Ee / 4) + hq * 64 + lane;
        float4 xq = ((const float4*)q)[g4];
        float4 xk = ((const float4*)k)[g4];
        float4 qs = ((const float4*)qscale)[lane & 15];
        float4 ks = ((const float4*)kscale)[lane & 15];
        float ssq = xq.x * xq.x + xq.y * xq.y + xq.z * xq.z + xq.w * xq.w;
        float ssk = xk.x * xk.x + xk.y * xk.y + xk.z * xk.z + xk.w * xk.w;
        #pragma unroll
        for (int m = 1; m < 16; m <<= 1) {
            ssq += __shfl_xor(ssq, m, 64);
            ssk += __shfl_xor(ssk, m, 64);
        }
        float rq = rsqrtf(ssq * (1.0f / 64.0f) + EPSf);
        float rk = rsqrtf(ssk * (1.0f / 64.0f) + EPSf);
        float oq[4], ok[4];
        oq[0] = xq.x * qs.x * rq; oq[1] = xq.y * qs.y * rq;
        oq[2] = xq.z * qs.z * rq; oq[3] = xq.w * qs.w * rq;
        ok[0] = xk.x * ks.x * rk; ok[1] = xk.y * ks.y * rk;
        ok[2] = xk.z * ks.z * rk; ok[3] = xk.w * ks.w * rk;
        if (d0 < RD) {                     // two rope pairs, thread-local
            float pw = ((float)n - (float)(Nn / 2)) * (1.0f / 512.0f);
            #pragma unroll
            for (int p = 0; p < 2; ++p) {
                int i = (d0 >> 1) + p;
                float invf = exp2f(-0.83048202372184f * (float)i);
                float ang  = (float)n * invf;
                float c = cosf(ang), s = sinf(ang);
                float base = (2.0f * (float)i + 12.8f) * (1.0f / 44.8f);
                float e  = pw * log2f(base);
                float sc = exp2f(e), rsc = exp2f(-e);
                float a = oq[2 * p], bq = oq[2 * p + 1];
                oq[2 * p]     = (a * c - bq * s) * sc;
                oq[2 * p + 1] = (bq * c + a * s) * sc;
                float ak = ok[2 * p], bk = ok[2 * p + 1];
                ok[2 * p]     = (ak * c - bk * s) * rsc;
                ok[2 * p + 1] = (bk * c + ak * s) * rsc;
            }
        }
        const float SCL = 0.125f * 1.44269504088896f;   // 1/sqrt(D) * log2(e)
        size_t o = ((size_t)(b * Hh + h) * Nn + n) * Dd + d0;
        uint2 uq, uk;
        uq.x = pk_bf16(oq[0] * SCL, oq[1] * SCL);
        uq.y = pk_bf16(oq[2] * SCL, oq[3] * SCL);
        uk.x = pk_bf16(ok[0], ok[1]);
        uk.y = pk_bf16(ok[2], ok[3]);
        *(uint2*)(qn + o) = uq;
        *(uint2*)(kn + o) = uk;
    } else if (bx < NB_PREP + NB_VT) {
        // ---- vt: V transpose, packed uint stores ----
        int vb = bx - NB_PREP;
        int bh = vb >> 5;
        int n0 = (vb & 31) * 64;
        int b = bh / Hh, h = bh % Hh;
        const float4* v4 = (const float4*)v;
        #pragma unroll
        for (int c = 0; c < 4; ++c) {
            int idx = t + c * 256;
            int n = idx >> 4, d4 = idx & 15;
            float4 vv = v4[(size_t)(b * Nn + n0 + n) * (Ee / 4) + h * 16 + d4];
            int la = n * 65 + d4 * 4;
            Vl[la] = vv.x; Vl[la + 1] = vv.y; Vl[la + 2] = vv.z; Vl[la + 3] = vv.w;
        }
        __syncthreads();
        #pragma unroll
        for (int c = 0; c < 8; ++c) {
            int linear = t + c * 256;          // 2048 = 64 d x 32 n-pairs
            int d = linear >> 5, n = (linear & 31) * 2;
            unsigned u = pk_bf16(Vl[n * 65 + d], Vl[(n + 1) * 65 + d]);
            *(unsigned*)(vt + ((size_t)bh * Dd + d) * Nn + n0 + n) = u;
        }
    } else {
        // ---- W fp32 -> bf16 convert ----
        int idx = (bx - NB_PREP - NB_VT) * 256 + t;   // one float4 each
        float4 vv = ((const float4*)w)[idx];
        uint2 uu;
        uu.x = pk_bf16(vv.x, vv.y);
        uu.y = pk_bf16(vv.z, vv.w);
        *(uint2*)(wb + (size_t)idx * 4) = uu;
    }
}

// MFMA flash attention (causal), NO-MAX softmax, WIDE q per wave.
// [round-9 verified structure: 62.3 us] QBLK=128 per block: 4 waves x 32 q
// (two 16-q groups A/B per wave). K/V LDS fragments read ONCE feed both
// groups' MFMAs. Row-sum l via MFMA with all-ones A operand.
// Double-buffered K/V DMA staging (the prefetch distance IS the latency
// hiding -- L2-direct variant without it was 2x slower, round 10).
// One barrier per tile, heavy-first dispatch (qt = 15 - blockIdx.y).
// LDS = 16K (K x2) + 16K (V x2) + 16K (P) = 49152 B -> 3 blocks/CU;
// grid (48,16) = 768 = exactly 3/CU co-resident.
__global__ __launch_bounds__(256, 3) void attn_kernel(
    const unsigned short* __restrict__ qn, const unsigned short* __restrict__ kn,
    const unsigned short* __restrict__ vt, unsigned short* __restrict__ y)
{
    __shared__ __align__(16) unsigned short Kl[2][64 * 64];
    __shared__ __align__(16) unsigned short Vl[2][64 * 64];    // V^T: [dim][key]
    __shared__ __align__(16) unsigned short Pl[8][16 * 64];    // per (wave,group)
    int t = threadIdx.x;
    int w = t >> 6, lane = t & 63;
    int quad = lane >> 4, col = lane & 15;
    int bh = blockIdx.x;
    int b = bh / Hh, h = bh % Hh;
    int qt = (NTQB - 1) - (int)blockIdx.y;     // heavy blocks dispatched first
    const unsigned short* kbh = kn + (size_t)bh * Nn * Dd;
    const unsigned short* vbh = vt + (size_t)bh * Dd * Nn;
    unsigned short* PlA = Pl[w * 2];
    unsigned short* PlB = Pl[w * 2 + 1];

    int l8 = lane >> 3, c8 = lane & 7;
    int g8 = (c8 ^ l8) * 8;                 // element offset of source chunk
    int sw = col & 7;
    int i0 = ((quad    ) ^ sw) * 8;         // chunks 0..31
    int i1 = ((quad + 4) ^ sw) * 8;         // chunks 32..63

    int q0 = qt * 128;
    int qgA = q0 + w * 32;                  // group A min row (wave-uniform)
    int qArow = qgA + col;
    int qBrow = qArow + 16;
    const unsigned short* qpA = qn + ((size_t)bh * Nn + qArow) * Dd;
    short8 qf0A = *(const short8*)(qpA + quad * 8);
    short8 qf1A = *(const short8*)(qpA + 32 + quad * 8);
    const unsigned short* qpB = qpA + 16 * Dd;
    short8 qf0B = *(const short8*)(qpB + quad * 8);
    short8 qf1B = *(const short8*)(qpB + 32 + quad * 8);

    short8 ones;                            // bf16 1.0 in all 8 slots
    #pragma unroll
    for (int i = 0; i < 8; ++i) ones[i] = (short)0x3F80;

    const f32x4 Zc = (f32x4){0.f, 0.f, 0.f, 0.f};
    f32x4 OA[4], OB[4], LsA = Zc, LsB = Zc;
    #pragma unroll
    for (int i = 0; i < 4; ++i) { OA[i] = Zc; OB[i] = Zc; }
    int ntiles = 2 * qt + 2;

    // prologue: stage tile 0 into buffer 0
    #pragma unroll
    for (int c = 0; c < 2; ++c) {
        int r = w * 16 + c * 8 + l8;
        int dstbase = (w * 16 + c * 8) * 64;
        gload16(kbh + ((size_t)r << 6) + g8, &Kl[0][dstbase]);
        gload16(vbh + (size_t)r * Nn + g8, &Vl[0][dstbase]);
    }

    for (int tile = 0; tile < ntiles; ++tile) {
        int cur = tile & 1;
        int j0 = tile * 64;
        // drain my DMA for buffer[cur]; barrier makes all waves' stages
        // visible AND guarantees buffer[cur^1] readers (tile-1) are done.
        asm volatile("s_waitcnt vmcnt(0)" ::: "memory");
        __syncthreads();
        if (tile + 1 < ntiles) {           // prefetch next tile -> other buffer
            int j0n = j0 + 64;
            #pragma unroll
            for (int c = 0; c < 2; ++c) {
                int r = w * 16 + c * 8 + l8;
                int dstbase = (w * 16 + c * 8) * 64;
                gload16(kbh + ((size_t)(j0n + r) << 6) + g8, &Kl[cur ^ 1][dstbase]);
                gload16(vbh + (size_t)r * Nn + j0n + g8, &Vl[cur ^ 1][dstbase]);
            }
        }
        // last tile (keys q0+64..q0+127): waves 0,1 (rows < q0+64) fully masked
        bool act = (tile != ntiles - 1) || (w >= 2);
        if (!act) continue;                // still hit next iteration's barrier

        // S^T = K . Q^T for both q-groups; K fragments read once, used twice.
        f32x4 SA[4], SB[4];
        __builtin_amdgcn_s_setprio(1);
        #pragma unroll
        for (int mt = 0; mt < 4; ++mt) {
            const unsigned short* rowp = &Kl[cur][(col + 16 * mt) * 64];
            short8 a0 = *(const short8*)(rowp + i0);
            short8 a1 = *(const short8*)(rowp + i1);
            SA[mt] = __builtin_amdgcn_mfma_f32_16x16x32_bf16(a0, qf0A, Zc, 0, 0, 0);
            SA[mt] = __builtin_amdgcn_mfma_f32_16x16x32_bf16(a1, qf1A, SA[mt], 0, 0, 0);
            SB[mt] = __builtin_amdgcn_mfma_f32_16x16x32_bf16(a0, qf0B, Zc, 0, 0, 0);
            SB[mt] = __builtin_amdgcn_mfma_f32_16x16x32_bf16(a1, qf1B, SB[mt], 0, 0, 0);
        }
        __builtin_amdgcn_s_setprio(0);
        if (j0 + 63 > qgA) {               // diagonal for group A
            #pragma unroll
            for (int mt = 0; mt < 4; ++mt)
                #pragma unroll
                for (int r = 0; r < 4; ++r) {
                    int key = j0 + mt * 16 + quad * 4 + r;
                    if (key > qArow) SA[mt][r] = NEG_BIG;
                }
        }
        if (j0 + 63 > qgA + 16) {          // diagonal for group B
            #pragma unroll
            for (int mt = 0; mt < 4; ++mt)
                #pragma unroll
                for (int r = 0; r < 4; ++r) {
                    int key = j0 + mt * 16 + quad * 4 + r;
                    if (key > qBrow) SB[mt][r] = NEG_BIG;
                }
        }
        // no-max softmax: P = exp2(S); pack to per-group LDS scratch
        #pragma unroll
        for (int mt = 0; mt < 4; ++mt) {
            uint2 ua, ub;
            ua.x = pk_bf16(exp2f(SA[mt][0]), exp2f(SA[mt][1]));
            ua.y = pk_bf16(exp2f(SA[mt][2]), exp2f(SA[mt][3]));
            ub.x = pk_bf16(exp2f(SB[mt][0]), exp2f(SB[mt][1]));
            ub.y = pk_bf16(exp2f(SB[mt][2]), exp2f(SB[mt][3]));
            int pidx = col * 64 + (((2 * mt + (quad >> 1)) ^ sw) << 3) + ((quad & 1) << 2);
            *(uint2*)(PlA + pidx) = ua;
            *(uint2*)(PlB + pidx) = ub;
        }
        asm volatile("s_waitcnt lgkmcnt(0)" ::: "memory");
        int pr0 = col * 64 + ((quad ^ sw) << 3);
        int pr1 = col * 64 + (((quad + 4) ^ sw) << 3);
        short8 pfA0 = *(const short8*)(PlA + pr0);
        short8 pfA1 = *(const short8*)(PlA + pr1);
        short8 pfB0 = *(const short8*)(PlB + pr0);
        short8 pfB1 = *(const short8*)(PlB + pr1);
        // row sums via MFMA with all-ones A: every lane gets l for q=col
        LsA = __builtin_amdgcn_mfma_f32_16x16x32_bf16(ones, pfA0, LsA, 0, 0, 0);
        LsA = __builtin_amdgcn_mfma_f32_16x16x32_bf16(ones, pfA1, LsA, 0, 0, 0);
        LsB = __builtin_amdgcn_mfma_f32_16x16x32_bf16(ones, pfB0, LsB, 0, 0, 0);
        LsB = __builtin_amdgcn_mfma_f32_16x16x32_bf16(ones, pfB1, LsB, 0, 0, 0);
        // O^T += V^T . P^T; V fragments read once, used twice.
        __builtin_amdgcn_s_setprio(1);
        #pragma unroll
        for (int mt = 0; mt < 4; ++mt) {
            const unsigned short* rowp = &Vl[cur][(col + 16 * mt) * 64];
            short8 a0 = *(const short8*)(rowp + i0);
            short8 a1 = *(const short8*)(rowp + i1);
            OA[mt] = __builtin_amdgcn_mfma_f32_16x16x32_bf16(a0, pfA0, OA[mt], 0, 0, 0);
            OA[mt] = __builtin_amdgcn_mfma_f32_16x16x32_bf16(a1, pfA1, OA[mt], 0, 0, 0);
            OB[mt] = __builtin_amdgcn_mfma_f32_16x16x32_bf16(a0, pfB0, OB[mt], 0, 0, 0);
            OB[mt] = __builtin_amdgcn_mfma_f32_16x16x32_bf16(a1, pfB1, OB[mt], 0, 0, 0);
        }
        __builtin_amdgcn_s_setprio(0);
    }
    float rlA = 1.0f / LsA[0];
    float rlB = 1.0f / LsB[0];
    unsigned short* ypA = y + ((size_t)(b * Nn + qArow)) * Ee + h * Dd;
    unsigned short* ypB = y + ((size_t)(b * Nn + qBrow)) * Ee + h * Dd;
    #pragma unroll
    for (int mt = 0; mt < 4; ++mt) {
        f32x4 oa = OA[mt] * rlA;
        f32x4 ob = OB[mt] * rlB;
        uint2 ua, ub;
        ua.x = pk_bf16(oa[0], oa[1]);
        ua.y = pk_bf16(oa[2], oa[3]);
        ub.x = pk_bf16(ob[0], ob[1]);
        ub.y = pk_bf16(ob[2], ob[3]);
        *(uint2*)(ypA + mt * 16 + quad * 4) = ua;
        *(uint2*)(ypB + mt * 16 + quad * 4) = ub;
    }
}

// MFMA NT GEMM: out[m][e] = sum_f y[m][f]*W[e][f] + bias[e]
// [round-6 verified core] 64(m) x 128(e) tile, BK=64, double-buffered
// async-DMA staging (one barrier per k-step), XOR swizzle.
// XCD-LOCALITY FIX: grid is now (128, 6) with m-tile on x, e-tile on y.
// The 6 blocks sharing one A-panel (yatt rows) have ids {x, x+128, ...};
// 128 % 8 == 0 so they ALL land on XCD x%8 -> A-panel fetched once per
// XCD instead of 6x from HBM (was grid (6,128): 6 consecutive ids ->
// 6 different XCDs). W (1.1 MB bf16) is L2-resident per XCD regardless.
__global__ __launch_bounds__(256) void proj_kernel(
    const unsigned short* __restrict__ y, const unsigned short* __restrict__ w,
    const float* __restrict__ bias, float* __restrict__ out)
{
    __shared__ __align__(16) unsigned short Al[2][64 * 64];
    __shared__ __align__(16) unsigned short Bl[2][128 * 64];
    int t = threadIdx.x;
    int wv = t >> 6, lane = t & 63;
    int quad = lane >> 4, col = lane & 15;
    int e0 = blockIdx.y * 128, m0 = blockIdx.x * 64;
    int l8 = lane >> 3, c8 = lane & 7;
    int g8 = (c8 ^ l8) * 8;
    f32x4 acc[4][2];
    #pragma unroll
    for (int i = 0; i < 4; ++i)
        #pragma unroll
        for (int j = 0; j < 2; ++j) acc[i][j] = (f32x4){0.f, 0.f, 0.f, 0.f};

    // prologue: stage k0 = 0 into buffer 0
    #pragma unroll
    for (int c = 0; c < 2; ++c) {
        int r = wv * 16 + c * 8 + l8;
        gload16(y + (size_t)(m0 + r) * Ee + g8, &Al[0][(wv * 16 + c * 8) * 64]);
    }
    #pragma unroll
    for (int c = 0; c < 4; ++c) {
        int r = wv * 32 + c * 8 + l8;
        gload16(w + (size_t)(e0 + r) * Ee + g8, &Bl[0][(wv * 32 + c * 8) * 64]);
    }

    for (int ks = 0; ks < Ee / 64; ++ks) {
        int cur = ks & 1;
        asm volatile("s_waitcnt vmcnt(0)" ::: "memory");
        __syncthreads();
        if (ks + 1 < Ee / 64) {            // prefetch next k-tile
            int k0n = (ks + 1) * 64;
            #pragma unroll
            for (int c = 0; c < 2; ++c) {
                int r = wv * 16 + c * 8 + l8;
                gload16(y + (size_t)(m0 + r) * Ee + k0n + g8,
                        &Al[cur ^ 1][(wv * 16 + c * 8) * 64]);
            }
            #pragma unroll
            for (int c = 0; c < 4; ++c) {
                int r = wv * 32 + c * 8 + l8;
                gload16(w + (size_t)(e0 + r) * Ee + k0n + g8,
                        &Bl[cur ^ 1][(wv * 32 + c * 8) * 64]);
            }
        }
        __builtin_amdgcn_s_setprio(1);
        #pragma unroll
        for (int kc = 0; kc < 2; ++kc) {
            short8 a[4], bb[2];
            #pragma unroll
            for (int mi = 0; mi < 4; ++mi) {
                int row = mi * 16 + col;
                int sl = ((kc * 4 + quad) ^ (row & 7)) * 8;
                a[mi] = *(const short8*)(&Al[cur][row * 64 + sl]);
            }
            #pragma unroll
            for (int ni = 0; ni < 2; ++ni) {
                int row = wv * 32 + ni * 16 + col;
                int sl = ((kc * 4 + quad) ^ (row & 7)) * 8;
                bb[ni] = *(const short8*)(&Bl[cur][row * 64 + sl]);
            }
            #pragma unroll
            for (int mi = 0; mi < 4; ++mi)
                #pragma unroll
                for (int ni = 0; ni < 2; ++ni)
                    acc[mi][ni] = __builtin_amdgcn_mfma_f32_16x16x32_bf16(a[mi], bb[ni], acc[mi][ni], 0, 0, 0);
        }
        __builtin_amdgcn_s_setprio(0);
    }
    // C layout: e-col = col, m-row = quad*4 + r
    #pragma unroll
    for (int ni = 0; ni < 2; ++ni) {
        int e = e0 + wv * 32 + ni * 16 + col;
        float be = bias[e];
        #pragma unroll
        for (int mi = 0; mi < 4; ++mi) {
            int mrow = m0 + mi * 16 + quad * 4;
            #pragma unroll
            for (int r = 0; r < 4; ++r)
                out[(size_t)(mrow + r) * Ee + e] = acc[mi][ni][r] + be;
        }
    }
}

extern "C" void kernel_launch(void* const* d_in, const int* in_sizes, int n_in,
                              void* d_out, int out_size, void* d_ws, size_t ws_size,
                              hipStream_t stream) {
    const float* q      = (const float*)d_in[0];
    const float* k      = (const float*)d_in[1];
    const float* v      = (const float*)d_in[2];
    const float* qscale = (const float*)d_in[3];
    const float* kscale = (const float*)d_in[4];
    const float* projw  = (const float*)d_in[5];
    const float* projb  = (const float*)d_in[6];
    float* out = (float*)d_out;

    char* base = (char*)d_ws;
    unsigned short* qn   = (unsigned short*)(base + 393216);
    unsigned short* kn   = (unsigned short*)(base + 12976128);
    unsigned short* vt   = (unsigned short*)(base + 25559040);
    unsigned short* yatt = (unsigned short*)(base + 38141952);
    unsigned short* wb   = (unsigned short*)(base + 50724864);

    prep_all<<<NB_PREP + NB_VT + NB_WCONV, 256, 0, stream>>>(
        q, k, qscale, kscale, qn, kn, v, vt, projw, wb);

    dim3 agrid(Bb * Hh, NTQB);                           // (48, 16): bh -> XCD
    attn_kernel<<<agrid, 256, 0, stream>>>(qn, kn, vt, yatt);

    dim3 ggrid((Bb * Nn) / 64, Ee / 128);                // (128, 6): m on x
    proj_kernel<<<ggrid, 256, 0, stream>>>(yatt, wb, projb, out);
}

// Round 12
// 188.958 us; speedup vs baseline: 1.2922x; 1.0086x over previous
//
#include <hip/hip_runtime.h>
#include <hip/hip_bf16.h>
#include <math.h>

#define Bb 4
#define Nn 2048
#define Ee 768
#define Hh 12
#define Dd 64
#define RD 32
#define EPSf 1e-6f
#define NEG_BIG -3.0e38f
#define NTQB 16   // number of 128-row q blocks per (b,h)

#define NB_PREP  (Bb * Nn * 3 / 4)             // 6144: wave = (b, n, head-quad)
#define NB_VT    (Bb * Hh * 32)                // 1536
#define NB_WCONV (Ee * Ee / 4 / 256)           // 576

typedef __attribute__((ext_vector_type(8))) short short8;
typedef __attribute__((ext_vector_type(4))) float f32x4;

// scalar round-to-nearest-even fp32 -> bf16 bits (cheap kernels only)
__device__ inline unsigned f2bf(float x) {
    union { float f; unsigned u; } c; c.f = x;
    unsigned r = c.u + 0x7FFFu + ((c.u >> 16) & 1u);
    return r >> 16;
}

// packed fp32x2 -> bf16x2 (v_cvt_pk_bf16_f32)
__device__ inline unsigned pk_bf16(float a, float b) {
    union { __hip_bfloat162 h; unsigned u; } c;
    c.h = __float22bfloat162_rn(float2{a, b});
    return c.u;
}

// async global->LDS DMA, 16 B per lane; lds dest = uniform base + lane*16
__device__ inline void gload16(const void* g, void* l) {
    __builtin_amdgcn_global_load_lds(
        (const __attribute__((address_space(1))) void*)g,
        (__attribute__((address_space(3))) void*)l,
        16, 0, 0);
}

// ONE fused pre-pass kernel. [round-9 verified structure]
//  blocks [0, NB_PREP): RMS-norm + xPos rope, VECTORIZED: one wave per
//      (b, n, head-quad), float4 per lane (16 B loads). Rotation pairs are
//      thread-local. HW-TRIG: sinf/cosf(ang) with ang up to 2047 rad takes
//      OCML's Payne-Hanek path (~100+ VALU each); replaced by manual
//      revolution-reduction (v_fract) + v_sin_f32/v_cos_f32 (1 instr each).
//      fract precision at rev~326 is ~2e-4 rad -- far below bf16 quant.
//  blocks [NB_PREP, +NB_VT): V transpose (B,N,E) fp32 -> (B,H,D,N) bf16.
//  blocks [+NB_WCONV): proj W fp32 -> bf16 convert.
__global__ __launch_bounds__(256) void prep_all(
    const float* __restrict__ q, const float* __restrict__ k,
    const float* __restrict__ qscale, const float* __restrict__ kscale,
    unsigned short* __restrict__ qn, unsigned short* __restrict__ kn,
    const float* __restrict__ v, unsigned short* __restrict__ vt,
    const float* __restrict__ w, unsigned short* __restrict__ wb)
{
    __shared__ float Vl[64 * 65];
    int bx = blockIdx.x;
    int t = threadIdx.x;
    if (bx < NB_PREP) {
        // ---- prep: one wave per (b, n, head-quad); lane owns 4 dims ----
        int wid = bx * 4 + (t >> 6);
        int lane = t & 63;
        int hq = wid % 3;                  // head-quad 0..2 (4 heads each)
        int bn = wid / 3;
        int n  = bn % Nn;
        int b  = bn / Nn;
        int h  = hq * 4 + (lane >> 4);     // head for this 16-lane group
        int d0 = (lane & 15) * 4;          // first dim of this lane's 4
        size_t g4 = (size_t)(b * Nn + n) * (Ee / 4) + hq * 64 + lane;
        float4 xq = ((const float4*)q)[g4];
        float4 xk = ((const float4*)k)[g4];
        float4 qs = ((const float4*)qscale)[lane & 15];
        float4 ks = ((const float4*)kscale)[lane & 15];
        float ssq = xq.x * xq.x + xq.y * xq.y + xq.z * xq.z + xq.w * xq.w;
        float ssk = xk.x * xk.x + xk.y * xk.y + xk.z * xk.z + xk.w * xk.w;
        #pragma unroll
        for (int m = 1; m < 16; m <<= 1) {
            ssq += __shfl_xor(ssq, m, 64);
            ssk += __shfl_xor(ssk, m, 64);
        }
        float rq = rsqrtf(ssq * (1.0f / 64.0f) + EPSf);
        float rk = rsqrtf(ssk * (1.0f / 64.0f) + EPSf);
        float oq[4], ok[4];
        oq[0] = xq.x * qs.x * rq; oq[1] = xq.y * qs.y * rq;
        oq[2] = xq.z * qs.z * rq; oq[3] = xq.w * qs.w * rq;
        ok[0] = xk.x * ks.x * rk; ok[1] = xk.y * ks.y * rk;
        ok[2] = xk.z * ks.z * rk; ok[3] = xk.w * ks.w * rk;
        if (d0 < RD) {                     // two rope pairs, thread-local
            float pw = ((float)n - (float)(Nn / 2)) * (1.0f / 512.0f);
            #pragma unroll
            for (int p = 0; p < 2; ++p) {
                int i = (d0 >> 1) + p;
                // inv_freq = 10000^(-i/16) = exp2(-i*log2(1e4)/16)
                float invf = __builtin_amdgcn_exp2f(-0.83048202372184f * (float)i);
                // revolutions = ang / 2pi; v_fract -> [0,1); HW sin/cos
                float rev = (float)n * invf * 0.15915494309189535f;
                rev -= floorf(rev);
                float c = __builtin_amdgcn_cosf(rev);
                float s = __builtin_amdgcn_sinf(rev);
                // scale = base^pw = exp2(pw * log2(base))
                float base = (2.0f * (float)i + 12.8f) * (1.0f / 44.8f);
                float e  = pw * __builtin_amdgcn_logf(base);
                float sc = __builtin_amdgcn_exp2f(e);
                float rsc = __builtin_amdgcn_exp2f(-e);
                float a = oq[2 * p], bq = oq[2 * p + 1];
                oq[2 * p]     = (a * c - bq * s) * sc;
                oq[2 * p + 1] = (bq * c + a * s) * sc;
                float ak = ok[2 * p], bk = ok[2 * p + 1];
                ok[2 * p]     = (ak * c - bk * s) * rsc;
                ok[2 * p + 1] = (bk * c + ak * s) * rsc;
            }
        }
        const float SCL = 0.125f * 1.44269504088896f;   // 1/sqrt(D) * log2(e)
        size_t o = ((size_t)(b * Hh + h) * Nn + n) * Dd + d0;
        uint2 uq, uk;
        uq.x = pk_bf16(oq[0] * SCL, oq[1] * SCL);
        uq.y = pk_bf16(oq[2] * SCL, oq[3] * SCL);
        uk.x = pk_bf16(ok[0], ok[1]);
        uk.y = pk_bf16(ok[2], ok[3]);
        *(uint2*)(qn + o) = uq;
        *(uint2*)(kn + o) = uk;
    } else if (bx < NB_PREP + NB_VT) {
        // ---- vt: V transpose, packed uint stores ----
        int vb = bx - NB_PREP;
        int bh = vb >> 5;
        int n0 = (vb & 31) * 64;
        int b = bh / Hh, h = bh % Hh;
        const float4* v4 = (const float4*)v;
        #pragma unroll
        for (int c = 0; c < 4; ++c) {
            int idx = t + c * 256;
            int n = idx >> 4, d4 = idx & 15;
            float4 vv = v4[(size_t)(b * Nn + n0 + n) * (Ee / 4) + h * 16 + d4];
            int la = n * 65 + d4 * 4;
            Vl[la] = vv.x; Vl[la + 1] = vv.y; Vl[la + 2] = vv.z; Vl[la + 3] = vv.w;
        }
        __syncthreads();
        #pragma unroll
        for (int c = 0; c < 8; ++c) {
            int linear = t + c * 256;          // 2048 = 64 d x 32 n-pairs
            int d = linear >> 5, n = (linear & 31) * 2;
            unsigned u = pk_bf16(Vl[n * 65 + d], Vl[(n + 1) * 65 + d]);
            *(unsigned*)(vt + ((size_t)bh * Dd + d) * Nn + n0 + n) = u;
        }
    } else {
        // ---- W fp32 -> bf16 convert ----
        int idx = (bx - NB_PREP - NB_VT) * 256 + t;   // one float4 each
        float4 vv = ((const float4*)w)[idx];
        uint2 uu;
        uu.x = pk_bf16(vv.x, vv.y);
        uu.y = pk_bf16(vv.z, vv.w);
        *(uint2*)(wb + (size_t)idx * 4) = uu;
    }
}

// MFMA flash attention (causal), NO-MAX softmax, WIDE q per wave.
// [round-9/11 verified structure: 62.2 us] QBLK=128 per block: 4 waves x 32 q
// (two 16-q groups A/B per wave). K/V LDS fragments read ONCE feed both
// groups' MFMAs. Row-sum l via MFMA with all-ones A operand.
// Double-buffered K/V DMA staging (the prefetch distance IS the latency
// hiding -- L2-direct variant without it was 2x slower, round 10).
// One barrier per tile, heavy-first dispatch (qt = 15 - blockIdx.y).
// LDS = 16K (K x2) + 16K (V x2) + 16K (P) = 49152 B -> 3 blocks/CU;
// grid (48,16) = 768 = exactly 3/CU co-resident.
__global__ __launch_bounds__(256, 3) void attn_kernel(
    const unsigned short* __restrict__ qn, const unsigned short* __restrict__ kn,
    const unsigned short* __restrict__ vt, unsigned short* __restrict__ y)
{
    __shared__ __align__(16) unsigned short Kl[2][64 * 64];
    __shared__ __align__(16) unsigned short Vl[2][64 * 64];    // V^T: [dim][key]
    __shared__ __align__(16) unsigned short Pl[8][16 * 64];    // per (wave,group)
    int t = threadIdx.x;
    int w = t >> 6, lane = t & 63;
    int quad = lane >> 4, col = lane & 15;
    int bh = blockIdx.x;
    int b = bh / Hh, h = bh % Hh;
    int qt = (NTQB - 1) - (int)blockIdx.y;     // heavy blocks dispatched first
    const unsigned short* kbh = kn + (size_t)bh * Nn * Dd;
    const unsigned short* vbh = vt + (size_t)bh * Dd * Nn;
    unsigned short* PlA = Pl[w * 2];
    unsigned short* PlB = Pl[w * 2 + 1];

    int l8 = lane >> 3, c8 = lane & 7;
    int g8 = (c8 ^ l8) * 8;                 // element offset of source chunk
    int sw = col & 7;
    int i0 = ((quad    ) ^ sw) * 8;         // chunks 0..31
    int i1 = ((quad + 4) ^ sw) * 8;         // chunks 32..63

    int q0 = qt * 128;
    int qgA = q0 + w * 32;                  // group A min row (wave-uniform)
    int qArow = qgA + col;
    int qBrow = qArow + 16;
    const unsigned short* qpA = qn + ((size_t)bh * Nn + qArow) * Dd;
    short8 qf0A = *(const short8*)(qpA + quad * 8);
    short8 qf1A = *(const short8*)(qpA + 32 + quad * 8);
    const unsigned short* qpB = qpA + 16 * Dd;
    short8 qf0B = *(const short8*)(qpB + quad * 8);
    short8 qf1B = *(const short8*)(qpB + 32 + quad * 8);

    short8 ones;                            // bf16 1.0 in all 8 slots
    #pragma unroll
    for (int i = 0; i < 8; ++i) ones[i] = (short)0x3F80;

    const f32x4 Zc = (f32x4){0.f, 0.f, 0.f, 0.f};
    f32x4 OA[4], OB[4], LsA = Zc, LsB = Zc;
    #pragma unroll
    for (int i = 0; i < 4; ++i) { OA[i] = Zc; OB[i] = Zc; }
    int ntiles = 2 * qt + 2;

    // prologue: stage tile 0 into buffer 0
    #pragma unroll
    for (int c = 0; c < 2; ++c) {
        int r = w * 16 + c * 8 + l8;
        int dstbase = (w * 16 + c * 8) * 64;
        gload16(kbh + ((size_t)r << 6) + g8, &Kl[0][dstbase]);
        gload16(vbh + (size_t)r * Nn + g8, &Vl[0][dstbase]);
    }

    for (int tile = 0; tile < ntiles; ++tile) {
        int cur = tile & 1;
        int j0 = tile * 64;
        // drain my DMA for buffer[cur]; barrier makes all waves' stages
        // visible AND guarantees buffer[cur^1] readers (tile-1) are done.
        asm volatile("s_waitcnt vmcnt(0)" ::: "memory");
        __syncthreads();
        if (tile + 1 < ntiles) {           // prefetch next tile -> other buffer
            int j0n = j0 + 64;
            #pragma unroll
            for (int c = 0; c < 2; ++c) {
                int r = w * 16 + c * 8 + l8;
                int dstbase = (w * 16 + c * 8) * 64;
                gload16(kbh + ((size_t)(j0n + r) << 6) + g8, &Kl[cur ^ 1][dstbase]);
                gload16(vbh + (size_t)r * Nn + j0n + g8, &Vl[cur ^ 1][dstbase]);
            }
        }
        // last tile (keys q0+64..q0+127): waves 0,1 (rows < q0+64) fully masked
        bool act = (tile != ntiles - 1) || (w >= 2);
        if (!act) continue;                // still hit next iteration's barrier

        // S^T = K . Q^T for both q-groups; K fragments read once, used twice.
        f32x4 SA[4], SB[4];
        __builtin_amdgcn_s_setprio(1);
        #pragma unroll
        for (int mt = 0; mt < 4; ++mt) {
            const unsigned short* rowp = &Kl[cur][(col + 16 * mt) * 64];
            short8 a0 = *(const short8*)(rowp + i0);
            short8 a1 = *(const short8*)(rowp + i1);
            SA[mt] = __builtin_amdgcn_mfma_f32_16x16x32_bf16(a0, qf0A, Zc, 0, 0, 0);
            SA[mt] = __builtin_amdgcn_mfma_f32_16x16x32_bf16(a1, qf1A, SA[mt], 0, 0, 0);
            SB[mt] = __builtin_amdgcn_mfma_f32_16x16x32_bf16(a0, qf0B, Zc, 0, 0, 0);
            SB[mt] = __builtin_amdgcn_mfma_f32_16x16x32_bf16(a1, qf1B, SB[mt], 0, 0, 0);
        }
        __builtin_amdgcn_s_setprio(0);
        if (j0 + 63 > qgA) {               // diagonal for group A
            #pragma unroll
            for (int mt = 0; mt < 4; ++mt)
                #pragma unroll
                for (int r = 0; r < 4; ++r) {
                    int key = j0 + mt * 16 + quad * 4 + r;
                    if (key > qArow) SA[mt][r] = NEG_BIG;
                }
        }
        if (j0 + 63 > qgA + 16) {          // diagonal for group B
            #pragma unroll
            for (int mt = 0; mt < 4; ++mt)
                #pragma unroll
                for (int r = 0; r < 4; ++r) {
                    int key = j0 + mt * 16 + quad * 4 + r;
                    if (key > qBrow) SB[mt][r] = NEG_BIG;
                }
        }
        // no-max softmax: P = exp2(S); pack to per-group LDS scratch
        #pragma unroll
        for (int mt = 0; mt < 4; ++mt) {
            uint2 ua, ub;
            ua.x = pk_bf16(exp2f(SA[mt][0]), exp2f(SA[mt][1]));
            ua.y = pk_bf16(exp2f(SA[mt][2]), exp2f(SA[mt][3]));
            ub.x = pk_bf16(exp2f(SB[mt][0]), exp2f(SB[mt][1]));
            ub.y = pk_bf16(exp2f(SB[mt][2]), exp2f(SB[mt][3]));
            int pidx = col * 64 + (((2 * mt + (quad >> 1)) ^ sw) << 3) + ((quad & 1) << 2);
            *(uint2*)(PlA + pidx) = ua;
            *(uint2*)(PlB + pidx) = ub;
        }
        asm volatile("s_waitcnt lgkmcnt(0)" ::: "memory");
        int pr0 = col * 64 + ((quad ^ sw) << 3);
        int pr1 = col * 64 + (((quad + 4) ^ sw) << 3);
        short8 pfA0 = *(const short8*)(PlA + pr0);
        short8 pfA1 = *(const short8*)(PlA + pr1);
        short8 pfB0 = *(const short8*)(PlB + pr0);
        short8 pfB1 = *(const short8*)(PlB + pr1);
        // row sums via MFMA with all-ones A: every lane gets l for q=col
        LsA = __builtin_amdgcn_mfma_f32_16x16x32_bf16(ones, pfA0, LsA, 0, 0, 0);
        LsA = __builtin_amdgcn_mfma_f32_16x16x32_bf16(ones, pfA1, LsA, 0, 0, 0);
        LsB = __builtin_amdgcn_mfma_f32_16x16x32_bf16(ones, pfB0, LsB, 0, 0, 0);
        LsB = __builtin_amdgcn_mfma_f32_16x16x32_bf16(ones, pfB1, LsB, 0, 0, 0);
        // O^T += V^T . P^T; V fragments read once, used twice.
        __builtin_amdgcn_s_setprio(1);
        #pragma unroll
        for (int mt = 0; mt < 4; ++mt) {
            const unsigned short* rowp = &Vl[cur][(col + 16 * mt) * 64];
            short8 a0 = *(const short8*)(rowp + i0);
            short8 a1 = *(const short8*)(rowp + i1);
            OA[mt] = __builtin_amdgcn_mfma_f32_16x16x32_bf16(a0, pfA0, OA[mt], 0, 0, 0);
            OA[mt] = __builtin_amdgcn_mfma_f32_16x16x32_bf16(a1, pfA1, OA[mt], 0, 0, 0);
            OB[mt] = __builtin_amdgcn_mfma_f32_16x16x32_bf16(a0, pfB0, OB[mt], 0, 0, 0);
            OB[mt] = __builtin_amdgcn_mfma_f32_16x16x32_bf16(a1, pfB1, OB[mt], 0, 0, 0);
        }
        __builtin_amdgcn_s_setprio(0);
    }
    float rlA = 1.0f / LsA[0];
    float rlB = 1.0f / LsB[0];
    unsigned short* ypA = y + ((size_t)(b * Nn + qArow)) * Ee + h * Dd;
    unsigned short* ypB = y + ((size_t)(b * Nn + qBrow)) * Ee + h * Dd;
    #pragma unroll
    for (int mt = 0; mt < 4; ++mt) {
        f32x4 oa = OA[mt] * rlA;
        f32x4 ob = OB[mt] * rlB;
        uint2 ua, ub;
        ua.x = pk_bf16(oa[0], oa[1]);
        ua.y = pk_bf16(oa[2], oa[3]);
        ub.x = pk_bf16(ob[0], ob[1]);
        ub.y = pk_bf16(ob[2], ob[3]);
        *(uint2*)(ypA + mt * 16 + quad * 4) = ua;
        *(uint2*)(ypB + mt * 16 + quad * 4) = ub;
    }
}

// MFMA NT GEMM: out[m][e] = sum_f y[m][f]*W[e][f] + bias[e]
// [round-11 verified] 64(m) x 128(e) tile, BK=64, double-buffered
// async-DMA staging (one barrier per k-step), XOR swizzle.
// grid (128, 6): m-tile on x, e-tile on y -- the 6 blocks sharing one
// A-panel have ids {x, x+128, ...} (128 % 8 == 0) -> same XCD -> A-panel
// fetched once per XCD instead of 6x from HBM.
__global__ __launch_bounds__(256) void proj_kernel(
    const unsigned short* __restrict__ y, const unsigned short* __restrict__ w,
    const float* __restrict__ bias, float* __restrict__ out)
{
    __shared__ __align__(16) unsigned short Al[2][64 * 64];
    __shared__ __align__(16) unsigned short Bl[2][128 * 64];
    int t = threadIdx.x;
    int wv = t >> 6, lane = t & 63;
    int quad = lane >> 4, col = lane & 15;
    int e0 = blockIdx.y * 128, m0 = blockIdx.x * 64;
    int l8 = lane >> 3, c8 = lane & 7;
    int g8 = (c8 ^ l8) * 8;
    f32x4 acc[4][2];
    #pragma unroll
    for (int i = 0; i < 4; ++i)
        #pragma unroll
        for (int j = 0; j < 2; ++j) acc[i][j] = (f32x4){0.f, 0.f, 0.f, 0.f};

    // prologue: stage k0 = 0 into buffer 0
    #pragma unroll
    for (int c = 0; c < 2; ++c) {
        int r = wv * 16 + c * 8 + l8;
        gload16(y + (size_t)(m0 + r) * Ee + g8, &Al[0][(wv * 16 + c * 8) * 64]);
    }
    #pragma unroll
    for (int c = 0; c < 4; ++c) {
        int r = wv * 32 + c * 8 + l8;
        gload16(w + (size_t)(e0 + r) * Ee + g8, &Bl[0][(wv * 32 + c * 8) * 64]);
    }

    for (int ks = 0; ks < Ee / 64; ++ks) {
        int cur = ks & 1;
        asm volatile("s_waitcnt vmcnt(0)" ::: "memory");
        __syncthreads();
        if (ks + 1 < Ee / 64) {            // prefetch next k-tile
            int k0n = (ks + 1) * 64;
            #pragma unroll
            for (int c = 0; c < 2; ++c) {
                int r = wv * 16 + c * 8 + l8;
                gload16(y + (size_t)(m0 + r) * Ee + k0n + g8,
                        &Al[cur ^ 1][(wv * 16 + c * 8) * 64]);
            }
            #pragma unroll
            for (int c = 0; c < 4; ++c) {
                int r = wv * 32 + c * 8 + l8;
                gload16(w + (size_t)(e0 + r) * Ee + k0n + g8,
                        &Bl[cur ^ 1][(wv * 32 + c * 8) * 64]);
            }
        }
        __builtin_amdgcn_s_setprio(1);
        #pragma unroll
        for (int kc = 0; kc < 2; ++kc) {
            short8 a[4], bb[2];
            #pragma unroll
            for (int mi = 0; mi < 4; ++mi) {
                int row = mi * 16 + col;
                int sl = ((kc * 4 + quad) ^ (row & 7)) * 8;
                a[mi] = *(const short8*)(&Al[cur][row * 64 + sl]);
            }
            #pragma unroll
            for (int ni = 0; ni < 2; ++ni) {
                int row = wv * 32 + ni * 16 + col;
                int sl = ((kc * 4 + quad) ^ (row & 7)) * 8;
                bb[ni] = *(const short8*)(&Bl[cur][row * 64 + sl]);
            }
            #pragma unroll
            for (int mi = 0; mi < 4; ++mi)
                #pragma unroll
                for (int ni = 0; ni < 2; ++ni)
                    acc[mi][ni] = __builtin_amdgcn_mfma_f32_16x16x32_bf16(a[mi], bb[ni], acc[mi][ni], 0, 0, 0);
        }
        __builtin_amdgcn_s_setprio(0);
    }
    // C layout: e-col = col, m-row = quad*4 + r
    #pragma unroll
    for (int ni = 0; ni < 2; ++ni) {
        int e = e0 + wv * 32 + ni * 16 + col;
        float be = bias[e];
        #pragma unroll
        for (int mi = 0; mi < 4; ++mi) {
            int mrow = m0 + mi * 16 + quad * 4;
            #pragma unroll
            for (int r = 0; r < 4; ++r)
                out[(size_t)(mrow + r) * Ee + e] = acc[mi][ni][r] + be;
        }
    }
}

extern "C" void kernel_launch(void* const* d_in, const int* in_sizes, int n_in,
                              void* d_out, int out_size, void* d_ws, size_t ws_size,
                              hipStream_t stream) {
    const float* q      = (const float*)d_in[0];
    const float* k      = (const float*)d_in[1];
    const float* v      = (const float*)d_in[2];
    const float* qscale = (const float*)d_in[3];
    const float* kscale = (const float*)d_in[4];
    const float* projw  = (const float*)d_in[5];
    const float* projb  = (const float*)d_in[6];
    float* out = (float*)d_out;

    char* base = (char*)d_ws;
    unsigned short* qn   = (unsigned short*)(base + 393216);
    unsigned short* kn   = (unsigned short*)(base + 12976128);
    unsigned short* vt   = (unsigned short*)(base + 25559040);
    unsigned short* yatt = (unsigned short*)(base + 38141952);
    unsigned short* wb   = (unsigned short*)(base + 50724864);

    prep_all<<<NB_PREP + NB_VT + NB_WCONV, 256, 0, stream>>>(
        q, k, qscale, kscale, qn, kn, v, vt, projw, wb);

    dim3 agrid(Bb * Hh, NTQB);                           // (48, 16): bh -> XCD
    attn_kernel<<<agrid, 256, 0, stream>>>(qn, kn, vt, yatt);

    dim3 ggrid((Bb * Nn) / 64, Ee / 128);                // (128, 6): m on x
    proj_kernel<<<ggrid, 256, 0, stream>>>(yatt, wb, projb, out);
}